// Round 15
// baseline (109.087 us; speedup 1.0000x reference)
//
#include <hip/hip_runtime.h>

typedef __attribute__((ext_vector_type(8))) short bf16x8;
typedef __attribute__((ext_vector_type(4))) float f32x4;
typedef __attribute__((ext_vector_type(4))) unsigned int u32x4;
typedef unsigned short u16;

#define MFMA16(a,b,c) __builtin_amdgcn_mfma_f32_16x16x32_bf16((a),(b),(c),0,0,0)

__device__ __forceinline__ u16 f2bf(float f){
  unsigned int u = __float_as_uint(f);
  u += 0x7fffu + ((u >> 16) & 1u);
  return (u16)(u >> 16);
}
__device__ __forceinline__ float bf2f(u16 v){
  return __uint_as_float(((unsigned int)v) << 16);
}
__device__ __forceinline__ unsigned int cvtpk(float lo, float hi){
  unsigned int r;
  asm("v_cvt_pk_bf16_f32 %0, %1, %2" : "=v"(r) : "v"(lo), "v"(hi));
  return r;
}
__device__ __forceinline__ void gload16(const void* g, void* l){
  __builtin_amdgcn_global_load_lds(
      (__attribute__((address_space(1))) void*)g,
      (__attribute__((address_space(3))) void*)l, 16, 0, 0);
}

// ---------------- prepass: all 4 weight transposes in ONE launch ----------
__global__ __launch_bounds__(256) void mqa_tcvt4(
    const float* __restrict__ Wq, const float* __restrict__ Wk,
    const float* __restrict__ Wv, const float* __restrict__ Wo,
    u16* __restrict__ WT, u16* __restrict__ WoT)
{
  __shared__ float t[32][33];
  int bx = blockIdx.x;
  const float* src; u16* dst; int C, cb, rb;
  if (bx < 1024)      { src = Wq; dst = WT;                      C = 1024; int q = bx;        cb = q & 31; rb = q >> 5; }
  else if (bx < 1088) { src = Wk; dst = WT + (size_t)1024*1024;  C = 64;   int q = bx - 1024; cb = q & 1;  rb = q >> 1; }
  else if (bx < 1152) { src = Wv; dst = WT + (size_t)1088*1024;  C = 64;   int q = bx - 1088; cb = q & 1;  rb = q >> 1; }
  else                { src = Wo; dst = WoT;                     C = 1024; int q = bx - 1152; cb = q & 31; rb = q >> 5; }
  int c0 = cb * 32, r0 = rb * 32;
  int x = threadIdx.x & 31, y0 = threadIdx.x >> 5;
  #pragma unroll
  for (int yy = y0; yy < 32; yy += 8)
    t[yy][x] = src[(size_t)(r0 + yy) * C + c0 + x];
  __syncthreads();
  #pragma unroll
  for (int yy = y0; yy < 32; yy += 8)
    dst[(size_t)(c0 + yy) * 1024 + r0 + x] = f2bf(t[x][yy]);
}

// ---------------- fused GEMM (R8 structure, known-good) ----------------
// MODE 1: A = Q_input fp32, LDS-staged (reg->cvtpk->swizzled ds_write);
//         epilogue = QKV scatter (V k-permuted, bits [k5 k3 k2 k4 k1 k0]).
//         Q outputs PRE-SCALED by C1 so attn uses exp2 on raw MFMA output.
// MODE 2: A = merge of 2 KV-split partials; epilogue = fp32 out.
// B via global_load_lds, XOR-swizzled.  BM=64 BN=128 BK=64, dbuf.
template<int MODE>
__global__ __launch_bounds__(256, 3) void mqa_gemm(
    const float* __restrict__ Af, const u16* __restrict__ Op,
    const float* __restrict__ Lp, const u16* __restrict__ Bt,
    float* __restrict__ outF, u16* __restrict__ Qb, u16* __restrict__ Kb,
    u16* __restrict__ Vtb, int M, int N, int K, int NT)
{
  __shared__ __align__(16) u16 lds_a[2][64*64];
  __shared__ __align__(16) u16 lds_b[2][128*64];
  int nwg = gridDim.x;
  int bx = ((int)blockIdx.x & 7) * (nwg >> 3) + ((int)blockIdx.x >> 3);
  int mt = bx / NT, nt = bx % NT;
  int m0 = mt * 64, n0 = nt * 128;
  int tid = threadIdx.x;
  int wid = tid >> 6, lane = tid & 63;
  int wr = (wid >> 1) * 32, wc = (wid & 1) * 64;
  int fr = lane & 15, g = lane >> 4;
  int sw = fr & 7;

  // A staging geometry: thread t -> row ar = t>>2, 16 cols at ac = (t&3)*16
  int ar = tid >> 2, ac = (tid & 3) * 16;
  int m_a = m0 + ar;
  int ab = m_a >> 11, as_ = m_a & 2047;
  int c8a = ac >> 3, rw8 = ar & 7;
  // B staging: 8-row chunks, pre-swizzled source col
  int srow = lane >> 3;
  int scol = ((lane & 7) ^ srow) * 8;

  f32x4 acc[2][4];
  #pragma unroll
  for (int i = 0; i < 2; ++i)
    #pragma unroll
    for (int j = 0; j < 4; ++j) acc[i][j] = (f32x4)0.f;

  // raw A-load state (transform deferred to write)
  float4 fA[4];
  bf16x8 pA0, pA1, pB0, pB1;
  float rlA = 0.f;

  auto loadA = [&](int k0){
    if (MODE == 1) {
      const float* src = &Af[(size_t)m_a * K + k0 + ac];
      fA[0] = *(const float4*)(src);
      fA[1] = *(const float4*)(src + 4);
      fA[2] = *(const float4*)(src + 8);
      fA[3] = *(const float4*)(src + 12);
    } else {
      int h = k0 >> 6;
      float l0 = Lp[(((size_t)(ab*2    ))*16 + h)*2048 + as_];
      float l1 = Lp[(((size_t)(ab*2 + 1))*16 + h)*2048 + as_];
      rlA = 1.f / (l0 + l1);
      const u16* p0 = &Op[(((size_t)(ab*2    ))*2048 + as_)*1024 + k0 + ac];
      const u16* p1 = &Op[(((size_t)(ab*2 + 1))*2048 + as_)*1024 + k0 + ac];
      pA0 = *(const bf16x8*)p0; pA1 = *(const bf16x8*)(p0 + 8);
      pB0 = *(const bf16x8*)p1; pB1 = *(const bf16x8*)(p1 + 8);
    }
  };

  auto writeA = [&](int bi){
    unsigned int w0[4], w1[4];
    if (MODE == 1) {
      w0[0] = cvtpk(fA[0].x, fA[0].y); w0[1] = cvtpk(fA[0].z, fA[0].w);
      w0[2] = cvtpk(fA[1].x, fA[1].y); w0[3] = cvtpk(fA[1].z, fA[1].w);
      w1[0] = cvtpk(fA[2].x, fA[2].y); w1[1] = cvtpk(fA[2].z, fA[2].w);
      w1[2] = cvtpk(fA[3].x, fA[3].y); w1[3] = cvtpk(fA[3].z, fA[3].w);
    } else {
      #pragma unroll
      for (int j = 0; j < 4; ++j) {
        float e0 = (bf2f((u16)pA0[2*j  ]) + bf2f((u16)pB0[2*j  ])) * rlA;
        float e1 = (bf2f((u16)pA0[2*j+1]) + bf2f((u16)pB0[2*j+1])) * rlA;
        w0[j] = cvtpk(e0, e1);
        float e2 = (bf2f((u16)pA1[2*j  ]) + bf2f((u16)pB1[2*j  ])) * rlA;
        float e3 = (bf2f((u16)pA1[2*j+1]) + bf2f((u16)pB1[2*j+1])) * rlA;
        w1[j] = cvtpk(e2, e3);
      }
    }
    u32x4 v0 = { w0[0], w0[1], w0[2], w0[3] };
    u32x4 v1 = { w1[0], w1[1], w1[2], w1[3] };
    *(bf16x8*)&lds_a[bi][ar*64 + ((c8a    ) ^ rw8)*8] = __builtin_bit_cast(bf16x8, v0);
    *(bf16x8*)&lds_a[bi][ar*64 + ((c8a + 1) ^ rw8)*8] = __builtin_bit_cast(bf16x8, v1);
  };

  auto stageB = [&](int bi, int k0){
    #pragma unroll
    for (int cc = 0; cc < 4; ++cc) {
      int rb = (wid*4 + cc) * 8;
      gload16(&Bt[(size_t)(n0 + rb + srow) * K + k0 + scol], &lds_b[bi][rb*64]);
    }
  };

  loadA(0);
  stageB(0, 0);
  writeA(0);
  __syncthreads();

  int cur = 0;
  for (int k0 = 0; k0 < K; k0 += 64) {
    bool nx = (k0 + 64 < K);
    if (nx) { loadA(k0 + 64); stageB(cur ^ 1, k0 + 64); }
    #pragma unroll
    for (int ks = 0; ks < 2; ++ks) {
      bf16x8 a0, a1, bfr[4];
      a0 = *(const bf16x8*)&lds_a[cur][(wr      + fr)*64 + (((ks*4+g) ^ sw))*8];
      a1 = *(const bf16x8*)&lds_a[cur][(wr + 16 + fr)*64 + (((ks*4+g) ^ sw))*8];
      #pragma unroll
      for (int j = 0; j < 4; ++j)
        bfr[j] = *(const bf16x8*)&lds_b[cur][(wc + j*16 + fr)*64 + (((ks*4+g) ^ sw))*8];
      #pragma unroll
      for (int j = 0; j < 4; ++j) {
        acc[0][j] = MFMA16(a0, bfr[j], acc[0][j]);
        acc[1][j] = MFMA16(a1, bfr[j], acc[1][j]);
      }
    }
    if (nx) writeA(cur ^ 1);
    __syncthreads();
    cur ^= 1;
  }

  const float C1 = 0.18033688011112042f;  // (1/8) * log2(e), folded into Q
  int fg = g;
  #pragma unroll
  for (int i = 0; i < 2; ++i) {
    #pragma unroll
    for (int j = 0; j < 4; ++j) {
      int ncol = n0 + wc + j*16 + fr;
      #pragma unroll
      for (int r = 0; r < 4; ++r) {
        int m = m0 + wr + i*16 + fg*4 + r;
        float v = acc[i][j][r];
        if (MODE == 2) {
          outF[(size_t)m * N + ncol] = v;
        } else {
          if (ncol < 1024) {
            Qb[(size_t)m * 1024 + ncol] = f2bf(v * C1);    // Q pre-scaled by C1
          } else if (ncol < 1088) {
            Kb[(size_t)m * 64 + (ncol - 1024)] = f2bf(v);  // K [B,S,HD]
          } else {
            int b = m >> 11, s = m & 2047;                 // Vp [B,HD,S-perm]
            int k = s & 63;
            int pos = (k & 35) | ((k & 12) << 1) | ((k & 16) >> 2);
            Vtb[((size_t)b * 64 + (ncol - 1088)) * 2048 + (s & ~63) + pos] = f2bf(v);
          }
        }
      }
    }
  }
}

// ---------------- flash MQA attention ----------------
// swapped-QK^T, K/V dbuf LDS via global_load_lds (XOR-swizzled), KV-split x2.
// C1 folded into Q; constant max shift cancels in O/l -> P = exp2(raw s).
// V fragments HOISTED before the softmax so their LDS latency hides under
// the exp2 VALU work (R6-proven pattern).
__global__ __launch_bounds__(256, 4) void mqa_attn(
    const u16* __restrict__ Qb, const u16* __restrict__ Kb,
    const u16* __restrict__ Vtb, u16* __restrict__ Opart,
    float* __restrict__ Lpart)
{
  int qt = blockIdx.x, h = blockIdx.y;
  int b = blockIdx.z >> 1, sp = blockIdx.z & 1;
  int part = blockIdx.z;
  int tid = threadIdx.x, wid = tid >> 6, lane = tid & 63;
  int fr = lane & 15, g = lane >> 4;
  int q0 = qt * 128 + wid * 32;

  __shared__ __align__(16) u16 KT[2][64*64];
  __shared__ __align__(16) u16 VT[2][64*64];

  const u16* Qbase = Qb + (size_t)b * 2048 * 1024 + (size_t)h * 64;
  const u16* Kbase = Kb + (size_t)b * 2048 * 64;
  const u16* Vbase = Vtb + (size_t)b * 64 * 2048;

  int srow = lane >> 3;
  int scol = ((lane & 7) ^ srow) * 8;

  bf16x8 qfv[2][2];
  #pragma unroll
  for (int qf_ = 0; qf_ < 2; ++qf_)
    #pragma unroll
    for (int ks = 0; ks < 2; ++ks)
      qfv[qf_][ks] = *(const bf16x8*)&Qbase[(size_t)(q0 + qf_*16 + fr) * 1024 + ks*32 + g*8];

  f32x4 oacc[2][4];
  #pragma unroll
  for (int qf_ = 0; qf_ < 2; ++qf_)
    #pragma unroll
    for (int vf = 0; vf < 4; ++vf) oacc[qf_][vf] = (f32x4)0.f;
  float lacc0 = 0.f, lacc1 = 0.f;

  const int kb0 = sp * 16;

  #pragma unroll
  for (int j = 0; j < 2; ++j) {
    int row = wid*16 + j*8 + srow;
    gload16(&Kbase[(size_t)(kb0*64 + row) * 64 + scol], &KT[0][(wid*16 + j*8) * 64]);
    gload16(&Vbase[(size_t)row * 2048 + kb0*64 + scol], &VT[0][(wid*16 + j*8) * 64]);
  }
  __syncthreads();

  int cur = 0;
  for (int kb = kb0; kb < kb0 + 16; ++kb) {
    if (kb + 1 < kb0 + 16) {
      int ntl = kb + 1;
      #pragma unroll
      for (int j = 0; j < 2; ++j) {
        int row = wid*16 + j*8 + srow;
        gload16(&Kbase[(size_t)(ntl*64 + row) * 64 + scol], &KT[cur^1][(wid*16 + j*8) * 64]);
        gload16(&Vbase[(size_t)row * 2048 + ntl*64 + scol], &VT[cur^1][(wid*16 + j*8) * 64]);
      }
    }

    const u16* kc = &KT[cur][0];
    const u16* vc = &VT[cur][0];

    f32x4 sacc[2][4];
    #pragma unroll
    for (int qf_ = 0; qf_ < 2; ++qf_)
      #pragma unroll
      for (int kf = 0; kf < 4; ++kf) sacc[qf_][kf] = (f32x4)0.f;

    __builtin_amdgcn_s_setprio(1);
    #pragma unroll
    for (int ks = 0; ks < 2; ++ks) {
      #pragma unroll
      for (int kf = 0; kf < 4; ++kf) {
        bf16x8 kfr = *(const bf16x8*)&kc[(kf*16 + fr)*64 + (((ks*4+g) ^ (fr&7)))*8];
        sacc[0][kf] = MFMA16(kfr, qfv[0][ks], sacc[0][kf]);
        sacc[1][kf] = MFMA16(kfr, qfv[1][ks], sacc[1][kf]);
      }
    }
    __builtin_amdgcn_s_setprio(0);

    // HOISTED V fragment reads: latency hides under the softmax VALU below
    bf16x8 vfr[8];
    #pragma unroll
    for (int i = 0; i < 8; ++i) {
      int ks2 = i >> 2, vf = i & 3;
      vfr[i] = *(const bf16x8*)&vc[(vf*16 + fr)*64 + (((ks2*4+g) ^ (fr&7)))*8];
    }

    // P = exp2(s) directly (C1 folded into Q; constant shift cancels in O/l)
    unsigned int pk0[8], pk1[8];
    float s0 = 0.f, s1 = 0.f;
    #pragma unroll
    for (int kf = 0; kf < 4; ++kf) {
      float a0 = __builtin_amdgcn_exp2f(sacc[0][kf][0]);
      float a1 = __builtin_amdgcn_exp2f(sacc[0][kf][1]);
      float a2 = __builtin_amdgcn_exp2f(sacc[0][kf][2]);
      float a3 = __builtin_amdgcn_exp2f(sacc[0][kf][3]);
      s0 += (a0 + a1) + (a2 + a3);
      pk0[2*kf]   = cvtpk(a0, a1);
      pk0[2*kf+1] = cvtpk(a2, a3);
      float b0 = __builtin_amdgcn_exp2f(sacc[1][kf][0]);
      float b1 = __builtin_amdgcn_exp2f(sacc[1][kf][1]);
      float b2 = __builtin_amdgcn_exp2f(sacc[1][kf][2]);
      float b3 = __builtin_amdgcn_exp2f(sacc[1][kf][3]);
      s1 += (b0 + b1) + (b2 + b3);
      pk1[2*kf]   = cvtpk(b0, b1);
      pk1[2*kf+1] = cvtpk(b2, b3);
    }
    lacc0 += s0;
    lacc1 += s1;

    __builtin_amdgcn_s_setprio(1);
    #pragma unroll
    for (int ks2 = 0; ks2 < 2; ++ks2) {
      u32x4 w0 = { pk0[4*ks2], pk0[4*ks2+1], pk0[4*ks2+2], pk0[4*ks2+3] };
      u32x4 w1 = { pk1[4*ks2], pk1[4*ks2+1], pk1[4*ks2+2], pk1[4*ks2+3] };
      bf16x8 pA0 = __builtin_bit_cast(bf16x8, w0);
      bf16x8 pA1 = __builtin_bit_cast(bf16x8, w1);
      #pragma unroll
      for (int vf = 0; vf < 4; ++vf) {
        oacc[0][vf] = MFMA16(pA0, vfr[ks2*4+vf], oacc[0][vf]);
        oacc[1][vf] = MFMA16(pA1, vfr[ks2*4+vf], oacc[1][vf]);
      }
    }
    __builtin_amdgcn_s_setprio(0);

    __syncthreads();
    cur ^= 1;
  }

  lacc0 += __shfl_xor(lacc0, 16); lacc0 += __shfl_xor(lacc0, 32);
  lacc1 += __shfl_xor(lacc1, 16); lacc1 += __shfl_xor(lacc1, 32);

  #pragma unroll
  for (int qf_ = 0; qf_ < 2; ++qf_) {
    #pragma unroll
    for (int r = 0; r < 4; ++r) {
      int row = q0 + qf_*16 + g*4 + r;
      #pragma unroll
      for (int vf = 0; vf < 4; ++vf) {
        int col = h*64 + vf*16 + fr;
        Opart[((size_t)part * 2048 + row) * 1024 + col] = f2bf(oacc[qf_][vf][r]);
      }
    }
  }
  if (g == 0) {
    int q = q0 + fr;
    size_t base = ((size_t)part * 16 + h) * 2048;
    Lpart[base + q]      = lacc0;
    Lpart[base + q + 16] = lacc1;
  }
}

extern "C" void kernel_launch(void* const* d_in, const int* in_sizes, int n_in,
                              void* d_out, int out_size, void* d_ws, size_t ws_size,
                              hipStream_t stream)
{
  const float* Qin = (const float*)d_in[0];
  const float* Wq  = (const float*)d_in[1];
  const float* Wk  = (const float*)d_in[2];
  const float* Wv  = (const float*)d_in[3];
  const float* Wo  = (const float*)d_in[4];
  float* out = (float*)d_out;

  // ws layout (peak 28.3 MB):
  //   WoT 2MB | Qb 8MB | Kb 0.5MB | Vtb 0.5MB | Lpart 0.5MB | union{WT, Opart}
  u16* WoT = (u16*)d_ws;                       // 1024*1024
  u16* Qb  = WoT + (size_t)1024*1024;          // 4096*1024
  u16* Kb  = Qb  + (size_t)4096*1024;          // 4096*64
  u16* Vtb = Kb  + (size_t)4096*64;            // 2*64*2048
  float* Lpart = (float*)(Vtb + (size_t)2*64*2048);  // 4*16*2048 floats
  u16* WT    = (u16*)(Lpart + (size_t)4*16*2048);    // 1152*1024 (then dead)
  u16* Opart = WT;                                   // 4*2048*1024 (after gemm1)

  mqa_tcvt4<<<2176, 256, 0, stream>>>(Wq, Wk, Wv, Wo, WT, WoT);

  mqa_gemm<1><<<64*9, 256, 0, stream>>>(Qin, nullptr, nullptr, WT,
                                        nullptr, Qb, Kb, Vtb,
                                        4096, 1152, 1024, 9);
  mqa_attn<<<dim3(16,16,4), 256, 0, stream>>>(Qb, Kb, Vtb, Opart, Lpart);
  mqa_gemm<2><<<64*8, 256, 0, stream>>>(nullptr, Opart, Lpart, WoT,
                                        out, nullptr, nullptr, nullptr,
                                        4096, 1024, 1024, 8);
}

// Round 16
// 100.354 us; speedup vs baseline: 1.0870x; 1.0870x over previous
//
#include <hip/hip_runtime.h>

typedef __attribute__((ext_vector_type(8))) short bf16x8;
typedef __attribute__((ext_vector_type(4))) float f32x4;
typedef __attribute__((ext_vector_type(4))) unsigned int u32x4;
typedef unsigned short u16;

#define MFMA16(a,b,c) __builtin_amdgcn_mfma_f32_16x16x32_bf16((a),(b),(c),0,0,0)

__device__ __forceinline__ u16 f2bf(float f){
  unsigned int u = __float_as_uint(f);
  u += 0x7fffu + ((u >> 16) & 1u);
  return (u16)(u >> 16);
}
__device__ __forceinline__ float bf2f(u16 v){
  return __uint_as_float(((unsigned int)v) << 16);
}
__device__ __forceinline__ unsigned int cvtpk(float lo, float hi){
  unsigned int r;
  asm("v_cvt_pk_bf16_f32 %0, %1, %2" : "=v"(r) : "v"(lo), "v"(hi));
  return r;
}
__device__ __forceinline__ void gload16(const void* g, void* l){
  __builtin_amdgcn_global_load_lds(
      (__attribute__((address_space(1))) void*)g,
      (__attribute__((address_space(3))) void*)l, 16, 0, 0);
}

// ---------------- prepass: all 4 weight transposes in ONE launch ----------
__global__ __launch_bounds__(256) void mqa_tcvt4(
    const float* __restrict__ Wq, const float* __restrict__ Wk,
    const float* __restrict__ Wv, const float* __restrict__ Wo,
    u16* __restrict__ WT, u16* __restrict__ WoT)
{
  __shared__ float t[32][33];
  int bx = blockIdx.x;
  const float* src; u16* dst; int C, cb, rb;
  if (bx < 1024)      { src = Wq; dst = WT;                      C = 1024; int q = bx;        cb = q & 31; rb = q >> 5; }
  else if (bx < 1088) { src = Wk; dst = WT + (size_t)1024*1024;  C = 64;   int q = bx - 1024; cb = q & 1;  rb = q >> 1; }
  else if (bx < 1152) { src = Wv; dst = WT + (size_t)1088*1024;  C = 64;   int q = bx - 1088; cb = q & 1;  rb = q >> 1; }
  else                { src = Wo; dst = WoT;                     C = 1024; int q = bx - 1152; cb = q & 31; rb = q >> 5; }
  int c0 = cb * 32, r0 = rb * 32;
  int x = threadIdx.x & 31, y0 = threadIdx.x >> 5;
  #pragma unroll
  for (int yy = y0; yy < 32; yy += 8)
    t[yy][x] = src[(size_t)(r0 + yy) * C + c0 + x];
  __syncthreads();
  #pragma unroll
  for (int yy = y0; yy < 32; yy += 8)
    dst[(size_t)(c0 + yy) * 1024 + r0 + x] = f2bf(t[x][yy]);
}

// ---------------- fused GEMM (R8 structure, known-good) ----------------
// MODE 1: A = Q_input fp32, LDS-staged (reg->cvtpk->swizzled ds_write);
//         epilogue = QKV scatter (V k-permuted, bits [k5 k3 k2 k4 k1 k0]).
//         Q outputs PRE-SCALED by C1 so attn uses exp2 on raw MFMA output.
// MODE 2: A = merge of 2 KV-split partials; epilogue = fp32 out.
// B via global_load_lds, XOR-swizzled.  BM=64 BN=128 BK=64, dbuf.
template<int MODE>
__global__ __launch_bounds__(256, 3) void mqa_gemm(
    const float* __restrict__ Af, const u16* __restrict__ Op,
    const float* __restrict__ Lp, const u16* __restrict__ Bt,
    float* __restrict__ outF, u16* __restrict__ Qb, u16* __restrict__ Kb,
    u16* __restrict__ Vtb, int M, int N, int K, int NT)
{
  __shared__ __align__(16) u16 lds_a[2][64*64];
  __shared__ __align__(16) u16 lds_b[2][128*64];
  int nwg = gridDim.x;
  int bx = ((int)blockIdx.x & 7) * (nwg >> 3) + ((int)blockIdx.x >> 3);
  int mt = bx / NT, nt = bx % NT;
  int m0 = mt * 64, n0 = nt * 128;
  int tid = threadIdx.x;
  int wid = tid >> 6, lane = tid & 63;
  int wr = (wid >> 1) * 32, wc = (wid & 1) * 64;
  int fr = lane & 15, g = lane >> 4;
  int sw = fr & 7;

  // A staging geometry: thread t -> row ar = t>>2, 16 cols at ac = (t&3)*16
  int ar = tid >> 2, ac = (tid & 3) * 16;
  int m_a = m0 + ar;
  int ab = m_a >> 11, as_ = m_a & 2047;
  int c8a = ac >> 3, rw8 = ar & 7;
  // B staging: 8-row chunks, pre-swizzled source col
  int srow = lane >> 3;
  int scol = ((lane & 7) ^ srow) * 8;

  f32x4 acc[2][4];
  #pragma unroll
  for (int i = 0; i < 2; ++i)
    #pragma unroll
    for (int j = 0; j < 4; ++j) acc[i][j] = (f32x4)0.f;

  // raw A-load state (transform deferred to write)
  float4 fA[4];
  bf16x8 pA0, pA1, pB0, pB1;
  float rlA = 0.f;

  auto loadA = [&](int k0){
    if (MODE == 1) {
      const float* src = &Af[(size_t)m_a * K + k0 + ac];
      fA[0] = *(const float4*)(src);
      fA[1] = *(const float4*)(src + 4);
      fA[2] = *(const float4*)(src + 8);
      fA[3] = *(const float4*)(src + 12);
    } else {
      int h = k0 >> 6;
      float l0 = Lp[(((size_t)(ab*2    ))*16 + h)*2048 + as_];
      float l1 = Lp[(((size_t)(ab*2 + 1))*16 + h)*2048 + as_];
      rlA = 1.f / (l0 + l1);
      const u16* p0 = &Op[(((size_t)(ab*2    ))*2048 + as_)*1024 + k0 + ac];
      const u16* p1 = &Op[(((size_t)(ab*2 + 1))*2048 + as_)*1024 + k0 + ac];
      pA0 = *(const bf16x8*)p0; pA1 = *(const bf16x8*)(p0 + 8);
      pB0 = *(const bf16x8*)p1; pB1 = *(const bf16x8*)(p1 + 8);
    }
  };

  auto writeA = [&](int bi){
    unsigned int w0[4], w1[4];
    if (MODE == 1) {
      w0[0] = cvtpk(fA[0].x, fA[0].y); w0[1] = cvtpk(fA[0].z, fA[0].w);
      w0[2] = cvtpk(fA[1].x, fA[1].y); w0[3] = cvtpk(fA[1].z, fA[1].w);
      w1[0] = cvtpk(fA[2].x, fA[2].y); w1[1] = cvtpk(fA[2].z, fA[2].w);
      w1[2] = cvtpk(fA[3].x, fA[3].y); w1[3] = cvtpk(fA[3].z, fA[3].w);
    } else {
      #pragma unroll
      for (int j = 0; j < 4; ++j) {
        float e0 = (bf2f((u16)pA0[2*j  ]) + bf2f((u16)pB0[2*j  ])) * rlA;
        float e1 = (bf2f((u16)pA0[2*j+1]) + bf2f((u16)pB0[2*j+1])) * rlA;
        w0[j] = cvtpk(e0, e1);
        float e2 = (bf2f((u16)pA1[2*j  ]) + bf2f((u16)pB1[2*j  ])) * rlA;
        float e3 = (bf2f((u16)pA1[2*j+1]) + bf2f((u16)pB1[2*j+1])) * rlA;
        w1[j] = cvtpk(e2, e3);
      }
    }
    u32x4 v0 = { w0[0], w0[1], w0[2], w0[3] };
    u32x4 v1 = { w1[0], w1[1], w1[2], w1[3] };
    *(bf16x8*)&lds_a[bi][ar*64 + ((c8a    ) ^ rw8)*8] = __builtin_bit_cast(bf16x8, v0);
    *(bf16x8*)&lds_a[bi][ar*64 + ((c8a + 1) ^ rw8)*8] = __builtin_bit_cast(bf16x8, v1);
  };

  auto stageB = [&](int bi, int k0){
    #pragma unroll
    for (int cc = 0; cc < 4; ++cc) {
      int rb = (wid*4 + cc) * 8;
      gload16(&Bt[(size_t)(n0 + rb + srow) * K + k0 + scol], &lds_b[bi][rb*64]);
    }
  };

  loadA(0);
  stageB(0, 0);
  writeA(0);
  __syncthreads();

  int cur = 0;
  for (int k0 = 0; k0 < K; k0 += 64) {
    bool nx = (k0 + 64 < K);
    if (nx) { loadA(k0 + 64); stageB(cur ^ 1, k0 + 64); }
    #pragma unroll
    for (int ks = 0; ks < 2; ++ks) {
      bf16x8 a0, a1, bfr[4];
      a0 = *(const bf16x8*)&lds_a[cur][(wr      + fr)*64 + (((ks*4+g) ^ sw))*8];
      a1 = *(const bf16x8*)&lds_a[cur][(wr + 16 + fr)*64 + (((ks*4+g) ^ sw))*8];
      #pragma unroll
      for (int j = 0; j < 4; ++j)
        bfr[j] = *(const bf16x8*)&lds_b[cur][(wc + j*16 + fr)*64 + (((ks*4+g) ^ sw))*8];
      #pragma unroll
      for (int j = 0; j < 4; ++j) {
        acc[0][j] = MFMA16(a0, bfr[j], acc[0][j]);
        acc[1][j] = MFMA16(a1, bfr[j], acc[1][j]);
      }
    }
    if (nx) writeA(cur ^ 1);
    __syncthreads();
    cur ^= 1;
  }

  const float C1 = 0.18033688011112042f;  // (1/8) * log2(e), folded into Q
  int fg = g;
  #pragma unroll
  for (int i = 0; i < 2; ++i) {
    #pragma unroll
    for (int j = 0; j < 4; ++j) {
      int ncol = n0 + wc + j*16 + fr;
      #pragma unroll
      for (int r = 0; r < 4; ++r) {
        int m = m0 + wr + i*16 + fg*4 + r;
        float v = acc[i][j][r];
        if (MODE == 2) {
          outF[(size_t)m * N + ncol] = v;
        } else {
          if (ncol < 1024) {
            Qb[(size_t)m * 1024 + ncol] = f2bf(v * C1);    // Q pre-scaled by C1
          } else if (ncol < 1088) {
            Kb[(size_t)m * 64 + (ncol - 1024)] = f2bf(v);  // K [B,S,HD]
          } else {
            int b = m >> 11, s = m & 2047;                 // Vp [B,HD,S-perm]
            int k = s & 63;
            int pos = (k & 35) | ((k & 12) << 1) | ((k & 16) >> 2);
            Vtb[((size_t)b * 64 + (ncol - 1088)) * 2048 + (s & ~63) + pos] = f2bf(v);
          }
        }
      }
    }
  }
}

// ---------------- flash MQA attention ----------------
// swapped-QK^T, K/V dbuf LDS via global_load_lds (XOR-swizzled), KV-split x2.
// Q was pre-scaled by C1, and the constant-max shift cancels between
// numerator and denominator, so P = exp2(raw MFMA output) directly:
// zero per-element FMA in the softmax.
__global__ __launch_bounds__(256, 4) void mqa_attn(
    const u16* __restrict__ Qb, const u16* __restrict__ Kb,
    const u16* __restrict__ Vtb, u16* __restrict__ Opart,
    float* __restrict__ Lpart)
{
  int qt = blockIdx.x, h = blockIdx.y;
  int b = blockIdx.z >> 1, sp = blockIdx.z & 1;
  int part = blockIdx.z;
  int tid = threadIdx.x, wid = tid >> 6, lane = tid & 63;
  int fr = lane & 15, g = lane >> 4;
  int q0 = qt * 128 + wid * 32;

  __shared__ __align__(16) u16 KT[2][64*64];
  __shared__ __align__(16) u16 VT[2][64*64];

  const u16* Qbase = Qb + (size_t)b * 2048 * 1024 + (size_t)h * 64;
  const u16* Kbase = Kb + (size_t)b * 2048 * 64;
  const u16* Vbase = Vtb + (size_t)b * 64 * 2048;

  int srow = lane >> 3;
  int scol = ((lane & 7) ^ srow) * 8;

  bf16x8 qfv[2][2];
  #pragma unroll
  for (int qf_ = 0; qf_ < 2; ++qf_)
    #pragma unroll
    for (int ks = 0; ks < 2; ++ks)
      qfv[qf_][ks] = *(const bf16x8*)&Qbase[(size_t)(q0 + qf_*16 + fr) * 1024 + ks*32 + g*8];

  f32x4 oacc[2][4];
  #pragma unroll
  for (int qf_ = 0; qf_ < 2; ++qf_)
    #pragma unroll
    for (int vf = 0; vf < 4; ++vf) oacc[qf_][vf] = (f32x4)0.f;
  float lacc0 = 0.f, lacc1 = 0.f;

  const int kb0 = sp * 16;

  #pragma unroll
  for (int j = 0; j < 2; ++j) {
    int row = wid*16 + j*8 + srow;
    gload16(&Kbase[(size_t)(kb0*64 + row) * 64 + scol], &KT[0][(wid*16 + j*8) * 64]);
    gload16(&Vbase[(size_t)row * 2048 + kb0*64 + scol], &VT[0][(wid*16 + j*8) * 64]);
  }
  __syncthreads();

  int cur = 0;
  for (int kb = kb0; kb < kb0 + 16; ++kb) {
    if (kb + 1 < kb0 + 16) {
      int ntl = kb + 1;
      #pragma unroll
      for (int j = 0; j < 2; ++j) {
        int row = wid*16 + j*8 + srow;
        gload16(&Kbase[(size_t)(ntl*64 + row) * 64 + scol], &KT[cur^1][(wid*16 + j*8) * 64]);
        gload16(&Vbase[(size_t)row * 2048 + ntl*64 + scol], &VT[cur^1][(wid*16 + j*8) * 64]);
      }
    }

    const u16* kc = &KT[cur][0];
    const u16* vc = &VT[cur][0];

    f32x4 sacc[2][4];
    #pragma unroll
    for (int qf_ = 0; qf_ < 2; ++qf_)
      #pragma unroll
      for (int kf = 0; kf < 4; ++kf) sacc[qf_][kf] = (f32x4)0.f;

    __builtin_amdgcn_s_setprio(1);
    #pragma unroll
    for (int ks = 0; ks < 2; ++ks) {
      #pragma unroll
      for (int kf = 0; kf < 4; ++kf) {
        bf16x8 kfr = *(const bf16x8*)&kc[(kf*16 + fr)*64 + (((ks*4+g) ^ (fr&7)))*8];
        sacc[0][kf] = MFMA16(kfr, qfv[0][ks], sacc[0][kf]);
        sacc[1][kf] = MFMA16(kfr, qfv[1][ks], sacc[1][kf]);
      }
    }
    __builtin_amdgcn_s_setprio(0);

    // P = exp2(s) directly (C1 folded into Q; constant shift cancels in O/l)
    unsigned int pk0[8], pk1[8];
    float s0 = 0.f, s1 = 0.f;
    #pragma unroll
    for (int kf = 0; kf < 4; ++kf) {
      float a0 = __builtin_amdgcn_exp2f(sacc[0][kf][0]);
      float a1 = __builtin_amdgcn_exp2f(sacc[0][kf][1]);
      float a2 = __builtin_amdgcn_exp2f(sacc[0][kf][2]);
      float a3 = __builtin_amdgcn_exp2f(sacc[0][kf][3]);
      s0 += (a0 + a1) + (a2 + a3);
      pk0[2*kf]   = cvtpk(a0, a1);
      pk0[2*kf+1] = cvtpk(a2, a3);
      float b0 = __builtin_amdgcn_exp2f(sacc[1][kf][0]);
      float b1 = __builtin_amdgcn_exp2f(sacc[1][kf][1]);
      float b2 = __builtin_amdgcn_exp2f(sacc[1][kf][2]);
      float b3 = __builtin_amdgcn_exp2f(sacc[1][kf][3]);
      s1 += (b0 + b1) + (b2 + b3);
      pk1[2*kf]   = cvtpk(b0, b1);
      pk1[2*kf+1] = cvtpk(b2, b3);
    }
    lacc0 += s0;
    lacc1 += s1;

    __builtin_amdgcn_s_setprio(1);
    #pragma unroll
    for (int ks2 = 0; ks2 < 2; ++ks2) {
      u32x4 w0 = { pk0[4*ks2], pk0[4*ks2+1], pk0[4*ks2+2], pk0[4*ks2+3] };
      u32x4 w1 = { pk1[4*ks2], pk1[4*ks2+1], pk1[4*ks2+2], pk1[4*ks2+3] };
      bf16x8 pA0 = __builtin_bit_cast(bf16x8, w0);
      bf16x8 pA1 = __builtin_bit_cast(bf16x8, w1);
      #pragma unroll
      for (int vf = 0; vf < 4; ++vf) {
        bf16x8 vfr = *(const bf16x8*)&vc[(vf*16 + fr)*64 + (((ks2*4+g) ^ (fr&7)))*8];
        oacc[0][vf] = MFMA16(pA0, vfr, oacc[0][vf]);
        oacc[1][vf] = MFMA16(pA1, vfr, oacc[1][vf]);
      }
    }
    __builtin_amdgcn_s_setprio(0);

    __syncthreads();
    cur ^= 1;
  }

  lacc0 += __shfl_xor(lacc0, 16); lacc0 += __shfl_xor(lacc0, 32);
  lacc1 += __shfl_xor(lacc1, 16); lacc1 += __shfl_xor(lacc1, 32);

  #pragma unroll
  for (int qf_ = 0; qf_ < 2; ++qf_) {
    #pragma unroll
    for (int r = 0; r < 4; ++r) {
      int row = q0 + qf_*16 + g*4 + r;
      #pragma unroll
      for (int vf = 0; vf < 4; ++vf) {
        int col = h*64 + vf*16 + fr;
        Opart[((size_t)part * 2048 + row) * 1024 + col] = f2bf(oacc[qf_][vf][r]);
      }
    }
  }
  if (g == 0) {
    int q = q0 + fr;
    size_t base = ((size_t)part * 16 + h) * 2048;
    Lpart[base + q]      = lacc0;
    Lpart[base + q + 16] = lacc1;
  }
}

extern "C" void kernel_launch(void* const* d_in, const int* in_sizes, int n_in,
                              void* d_out, int out_size, void* d_ws, size_t ws_size,
                              hipStream_t stream)
{
  const float* Qin = (const float*)d_in[0];
  const float* Wq  = (const float*)d_in[1];
  const float* Wk  = (const float*)d_in[2];
  const float* Wv  = (const float*)d_in[3];
  const float* Wo  = (const float*)d_in[4];
  float* out = (float*)d_out;

  // ws layout (peak 28.3 MB):
  //   WoT 2MB | Qb 8MB | Kb 0.5MB | Vtb 0.5MB | Lpart 0.5MB | union{WT, Opart}
  u16* WoT = (u16*)d_ws;                       // 1024*1024
  u16* Qb  = WoT + (size_t)1024*1024;          // 4096*1024
  u16* Kb  = Qb  + (size_t)4096*1024;          // 4096*64
  u16* Vtb = Kb  + (size_t)4096*64;            // 2*64*2048
  float* Lpart = (float*)(Vtb + (size_t)2*64*2048);  // 4*16*2048 floats
  u16* WT    = (u16*)(Lpart + (size_t)4*16*2048);    // 1152*1024 (then dead)
  u16* Opart = WT;                                   // 4*2048*1024 (after gemm1)

  mqa_tcvt4<<<2176, 256, 0, stream>>>(Wq, Wk, Wv, Wo, WT, WoT);

  mqa_gemm<1><<<64*9, 256, 0, stream>>>(Qin, nullptr, nullptr, WT,
                                        nullptr, Qb, Kb, Vtb,
                                        4096, 1152, 1024, 9);
  mqa_attn<<<dim3(16,16,4), 256, 0, stream>>>(Qb, Kb, Vtb, Opart, Lpart);
  mqa_gemm<2><<<64*8, 256, 0, stream>>>(nullptr, Opart, Lpart, WoT,
                                        out, nullptr, nullptr, nullptr,
                                        4096, 1024, 1024, 8);
}